// Round 1
// baseline (283.092 us; speedup 1.0000x reference)
//
#include <hip/hip_runtime.h>

// Problem constants
#define NB   2
#define NC   256
#define NC8  32
#define ND   16
#define NH   64
#define NW   64
#define DHW  65536       // D*H*W
#define HW   4096        // H*W
#define CDHW 16777216    // C*D*H*W

// LDS layout (bytes)
#define XT_LD 264        // Xth/Xtl row stride (ushort), 256 + 8 pad
#define QT_LD 36         // Qt/Kt row stride (float), 32 + 4 pad
#define A_LD  72         // Ah/Al row stride (ushort), 64 + 8 pad
#define VB_LD 72         // V buffer row stride (ushort)

#define OFF_XTH 0        // 64*264*2 = 33792
#define OFF_XTL 33792
#define OFF_QT  67584    // 64*36*4 = 9216
#define OFF_KT  76800
#define OFF_UNI 86016    // union: Xlin 128*64*4 = 32768  |  Ah/Al + Vbuf
#define OFF_AH  86016
#define OFF_AL  95232
#define OFF_VB  104448   // 4 waves * (16*72*2 hi + 16*72*2 lo) = 18432
#define LDS_BYTES 122880

typedef __attribute__((ext_vector_type(4))) float f32x4;
typedef __attribute__((ext_vector_type(8))) short bf16x8;
typedef unsigned short ushort_t;

#define MFMA16(a, b, c) __builtin_amdgcn_mfma_f32_16x16x32_bf16((a), (b), (c), 0, 0, 0)

__device__ __forceinline__ void split_val(float f, short& h, short& l) {
  // truncation split: f = hi + lo with |lo| <= 2^-8 |f|, lo truncated to bf16
  unsigned int u = __builtin_bit_cast(unsigned int, f);
  h = (short)(unsigned short)(u >> 16);
  float fh = __builtin_bit_cast(float, u & 0xffff0000u);
  float r = f - fh;
  l = (short)(unsigned short)(__builtin_bit_cast(unsigned int, r) >> 16);
}

__device__ __forceinline__ void load_split8(const float* __restrict__ p, bf16x8& h8, bf16x8& l8) {
  float4 a = *(const float4*)p;
  float4 b = *(const float4*)(p + 4);
  float f[8] = {a.x, a.y, a.z, a.w, b.x, b.y, b.z, b.w};
#pragma unroll
  for (int j = 0; j < 8; ++j) {
    short hh, ll;
    split_val(f[j], hh, ll);
    h8[j] = hh; l8[j] = ll;
  }
}

__global__ void __launch_bounds__(256, 1)
xattn_kernel(const float* __restrict__ x1, const float* __restrict__ x2,
             const float* __restrict__ Wq, const float* __restrict__ bq,
             const float* __restrict__ Wk, const float* __restrict__ bk,
             const float* __restrict__ Wv, const float* __restrict__ bv,
             float* __restrict__ out)
{
  extern __shared__ char smem[];
  ushort_t* Xth = (ushort_t*)(smem + OFF_XTH);   // [64][264]  X^T hi (row = x, col = c)
  ushort_t* Xtl = (ushort_t*)(smem + OFF_XTL);   // [64][264]  X^T lo
  float*    Qt  = (float*)(smem + OFF_QT);       // [64][36]   Q^T fp32 (row = x, col = c8)
  float*    Kt  = (float*)(smem + OFF_KT);       // [64][36]   K^T fp32 (row = y, col = c8)
  float*    Xlin = (float*)(smem + OFF_UNI);     // [128][64]  staging (union)
  ushort_t* Ah  = (ushort_t*)(smem + OFF_AH);    // [64][72]   A hi (row = x, col = y)
  ushort_t* Al  = (ushort_t*)(smem + OFF_AL);    // [64][72]   A lo
  ushort_t* Vb  = (ushort_t*)(smem + OFF_VB);    // per-wave V chunk buffers

  const int tid  = threadIdx.x;
  const int lane = tid & 63;
  const int wv   = tid >> 6;       // wave 0..3
  const int l15  = lane & 15;
  const int g    = lane >> 4;      // lane group 0..3

  const int grp = blockIdx.x;               // (b,d,h) group
  const int b   = grp >> 10;                // / (D*H)
  const int rem = grp & 1023;
  const int d   = rem >> 6;
  const int h   = rem & 63;
  const size_t base = (size_t)b * CDHW + (size_t)d * HW + (size_t)h * NW;

  // ---------- staging: global X -> Xth/Xtl (transposed + hi/lo split) ----------
  auto stage = [&](const float* __restrict__ xs) {
#pragma unroll
    for (int half = 0; half < 2; ++half) {
      const float* src = xs + base + (size_t)half * 128 * DHW;
      // pass A: coalesced global -> Xlin [c][x]
#pragma unroll
      for (int i = 0; i < 8; ++i) {
        int idx = tid + i * 256;            // 0..2047
        int row = idx >> 4;                 // c within half (0..127)
        int c4  = (idx & 15) << 2;          // x (0..60 step 4)
        float4 v = *(const float4*)(src + (size_t)row * DHW + c4);
        *(float4*)&Xlin[row * 64 + c4] = v;
      }
      __syncthreads();
      // pass B: Xlin -> Xth/Xtl transposed + split
      {
        int x  = tid & 63;
        int cw = wv * 32;
#pragma unroll
        for (int blk = 0; blk < 4; ++blk) {
          int c0 = cw + blk * 8;
          bf16x8 h8, l8;
#pragma unroll
          for (int j = 0; j < 8; ++j) {
            float f = Xlin[(c0 + j) * 64 + x];
            short hh, ll;
            split_val(f, hh, ll);
            h8[j] = hh; l8[j] = ll;
          }
          int cg = half * 128 + c0;
          *(bf16x8*)&Xth[x * XT_LD + cg] = h8;
          *(bf16x8*)&Xtl[x * XT_LD + cg] = l8;
        }
      }
      __syncthreads();
    }
  };

  // ---------- projection Q or K: Odst[x][c8] = (W * X + bias)^T ----------
  auto proj = [&](const float* __restrict__ Wm, const float* __restrict__ bias,
                  float* __restrict__ Odst) {
    f32x4 acc0, acc1;
    {
      int rb0 = 4 * g, rb1 = 16 + 4 * g;
      acc0 = (f32x4){bias[rb0], bias[rb0 + 1], bias[rb0 + 2], bias[rb0 + 3]};
      acc1 = (f32x4){bias[rb1], bias[rb1 + 1], bias[rb1 + 2], bias[rb1 + 3]};
    }
    const int x = wv * 16 + l15;   // n-col: this wave's x tile
#pragma unroll
    for (int ks = 0; ks < 8; ++ks) {
      const int ko = ks * 32 + 8 * g;
      bf16x8 bh = *(const bf16x8*)&Xth[x * XT_LD + ko];
      bf16x8 bl = *(const bf16x8*)&Xtl[x * XT_LD + ko];
      bf16x8 wh, wl;
      load_split8(Wm + (size_t)(l15) * 256 + ko, wh, wl);       // m-tile 0
      acc0 = MFMA16(wh, bh, acc0);
      acc0 = MFMA16(wh, bl, acc0);
      acc0 = MFMA16(wl, bh, acc0);
      load_split8(Wm + (size_t)(16 + l15) * 256 + ko, wh, wl);  // m-tile 1
      acc1 = MFMA16(wh, bh, acc1);
      acc1 = MFMA16(wh, bl, acc1);
      acc1 = MFMA16(wl, bh, acc1);
    }
    // D layout: col = l15 (x), row = 4g + r (c8 within 16-tile)
#pragma unroll
    for (int r = 0; r < 4; ++r) {
      Odst[x * QT_LD + 4 * g + r]      = acc0[r];
      Odst[x * QT_LD + 16 + 4 * g + r] = acc1[r];
    }
  };

  // ===== phase 1: X1 -> Q =====
  stage(x1);
  proj(Wq, bq, Qt);
  __syncthreads();

  // ===== phase 2: X2 -> K =====
  stage(x2);                       // X2 stays in Xth/Xtl for V stage
  proj(Wk, bk, Kt);
  __syncthreads();

  // ===== phase 3: A = Q^T K  (64x64), split-stored to Ah/Al =====
  {
    const int y = wv * 16 + l15;   // n-col: this wave's y tile
    bf16x8 kh, kl;
    load_split8(&Kt[y * QT_LD + 8 * g], kh, kl);
    f32x4 acc[4];
#pragma unroll
    for (int mt = 0; mt < 4; ++mt) acc[mt] = (f32x4){0.f, 0.f, 0.f, 0.f};
#pragma unroll
    for (int mt = 0; mt < 4; ++mt) {
      bf16x8 qh, ql;
      load_split8(&Qt[(mt * 16 + l15) * QT_LD + 8 * g], qh, ql);
      acc[mt] = MFMA16(qh, kh, acc[mt]);
      acc[mt] = MFMA16(qh, kl, acc[mt]);
      acc[mt] = MFMA16(ql, kh, acc[mt]);
    }
#pragma unroll
    for (int mt = 0; mt < 4; ++mt)
#pragma unroll
      for (int r = 0; r < 4; ++r) {
        int xr = mt * 16 + 4 * g + r;
        short hh, ll;
        split_val(acc[mt][r], hh, ll);
        Ah[xr * A_LD + y] = (ushort_t)hh;
        Al[xr * A_LD + y] = (ushort_t)ll;
      }
  }
  __syncthreads();

  // ===== phase 4: V = Wv*X2 + bv (this wave's 64 c-rows), then Out = V*A^T =====
  {
    const int cb = wv * 64;
    f32x4 vacc[4][4];
#pragma unroll
    for (int mt = 0; mt < 4; ++mt) {
      int rb = cb + mt * 16 + 4 * g;
      f32x4 bb = (f32x4){bv[rb], bv[rb + 1], bv[rb + 2], bv[rb + 3]};
#pragma unroll
      for (int nt = 0; nt < 4; ++nt) vacc[mt][nt] = bb;
    }
#pragma unroll
    for (int ks = 0; ks < 8; ++ks) {
      const int ko = ks * 32 + 8 * g;
      bf16x8 xh[4], xl[4];
#pragma unroll
      for (int nt = 0; nt < 4; ++nt) {
        xh[nt] = *(const bf16x8*)&Xth[(nt * 16 + l15) * XT_LD + ko];
        xl[nt] = *(const bf16x8*)&Xtl[(nt * 16 + l15) * XT_LD + ko];
      }
#pragma unroll
      for (int mt = 0; mt < 4; ++mt) {
        bf16x8 wh, wl;
        load_split8(Wv + (size_t)(cb + mt * 16 + l15) * 256 + ko, wh, wl);
#pragma unroll
        for (int nt = 0; nt < 4; ++nt) {
          vacc[mt][nt] = MFMA16(wh, xh[nt], vacc[mt][nt]);
          vacc[mt][nt] = MFMA16(wh, xl[nt], vacc[mt][nt]);
          vacc[mt][nt] = MFMA16(wl, xh[nt], vacc[mt][nt]);
        }
      }
    }
    // per 16-row c-tile: round-trip V through per-wave LDS buffer, then PV
    ushort_t* Vh = Vb + wv * 2304;   // [16][72] hi
    ushort_t* Vl = Vh + 1152;        // [16][72] lo
#pragma unroll
    for (int mt = 0; mt < 4; ++mt) {
#pragma unroll
      for (int nt = 0; nt < 4; ++nt)
#pragma unroll
        for (int r = 0; r < 4; ++r) {
          short hh, ll;
          split_val(vacc[mt][nt][r], hh, ll);
          int cc = 4 * g + r, yy = nt * 16 + l15;
          Vh[cc * VB_LD + yy] = (ushort_t)hh;
          Vl[cc * VB_LD + yy] = (ushort_t)ll;
        }
      f32x4 oacc[4];
#pragma unroll
      for (int nt = 0; nt < 4; ++nt) oacc[nt] = (f32x4){0.f, 0.f, 0.f, 0.f};
#pragma unroll
      for (int ys = 0; ys < 2; ++ys) {
        const int yo = ys * 32 + 8 * g;
        bf16x8 vh8 = *(const bf16x8*)&Vh[l15 * VB_LD + yo];
        bf16x8 vl8 = *(const bf16x8*)&Vl[l15 * VB_LD + yo];
#pragma unroll
        for (int nt = 0; nt < 4; ++nt) {
          bf16x8 ah8 = *(const bf16x8*)&Ah[(nt * 16 + l15) * A_LD + yo];
          bf16x8 al8 = *(const bf16x8*)&Al[(nt * 16 + l15) * A_LD + yo];
          oacc[nt] = MFMA16(vh8, ah8, oacc[nt]);
          oacc[nt] = MFMA16(vh8, al8, oacc[nt]);
          oacc[nt] = MFMA16(vl8, ah8, oacc[nt]);
        }
      }
#pragma unroll
      for (int nt = 0; nt < 4; ++nt)
#pragma unroll
        for (int r = 0; r < 4; ++r) {
          int c = cb + mt * 16 + 4 * g + r;
          out[base + (size_t)c * DHW + nt * 16 + l15] = oacc[nt][r];
        }
    }
  }
}

extern "C" void kernel_launch(void* const* d_in, const int* in_sizes, int n_in,
                              void* d_out, int out_size, void* d_ws, size_t ws_size,
                              hipStream_t stream)
{
  const float* x1 = (const float*)d_in[0];
  const float* x2 = (const float*)d_in[1];
  const float* Wq = (const float*)d_in[2];
  const float* bq = (const float*)d_in[3];
  const float* Wk = (const float*)d_in[4];
  const float* bk = (const float*)d_in[5];
  const float* Wv = (const float*)d_in[6];
  const float* bv = (const float*)d_in[7];
  float* out = (float*)d_out;

  (void)hipFuncSetAttribute((const void*)xattn_kernel,
                            hipFuncAttributeMaxDynamicSharedMemorySize, LDS_BYTES);
  hipLaunchKernelGGL(xattn_kernel, dim3(NB * ND * NH), dim3(256), LDS_BYTES, stream,
                     x1, x2, Wq, bq, Wk, bk, Wv, bv, out);
}

// Round 2
// 206.529 us; speedup vs baseline: 1.3707x; 1.3707x over previous
//
#include <hip/hip_runtime.h>

// Problem constants
#define NB   2
#define ND   16
#define NH   64
#define DHW  65536       // D*H*W
#define HW   4096        // H*W
#define CDHW 16777216    // C*D*H*W

// LDS strides (elements)
#define XT_LD 72         // Xth/Xtl row stride (ushort): 64 + 8 pad
#define XL_LD 66         // Xlin row stride (float): 64 + 2 pad
#define QK_LD 40         // Qh/Ql/Kh/Kl row stride (ushort): 32 + 8 pad
#define A_LD  72         // Ah/Al row stride (ushort)
#define VB_LD 72         // V round-trip buffer row stride (ushort)

// LDS offsets (bytes). Three unioned regions, total 47104 B -> 3 blocks/CU.
// R1 [0,18432):      Xth[64][72], Xtl[64][72]   ->  Ah[64][72], Al[64][72]
// R2 [18432,36864):  Xlin[64][66] f32  ->  Kh/Kl[64][40]  ->  Vb 4 waves x 4608 B
// R3 [36864,47104):  Qh[64][40], Ql[64][40]
#define OFF_XTH 0
#define OFF_XTL 9216
#define OFF_R2  18432
#define OFF_KH  18432
#define OFF_KL  23552
#define OFF_AH  0
#define OFF_AL  9216
#define OFF_QH  36864
#define OFF_QL  41984
#define SMEM_BYTES 47104

typedef __attribute__((ext_vector_type(4))) float f32x4;
typedef __attribute__((ext_vector_type(8))) short bf16x8;
typedef unsigned short ushort_t;

#define MFMA16(a, b, c) __builtin_amdgcn_mfma_f32_16x16x32_bf16((a), (b), (c), 0, 0, 0)

// ws layout (ushort elements): WqH 0, WqL 8192, WkH 16384, WkL 24576, WvH 32768, WvL 98304
#define WS_WQH 0
#define WS_WQL 8192
#define WS_WKH 16384
#define WS_WKL 24576
#define WS_WVH 32768
#define WS_WVL 98304
#define WS_NEED_BYTES 327680  // 163840 ushorts

__device__ __forceinline__ void split_val(float f, short& h, short& l) {
  // truncation split: f = hi + lo, lo truncated to bf16 (residual ~2^-17 rel)
  unsigned int u = __builtin_bit_cast(unsigned int, f);
  h = (short)(unsigned short)(u >> 16);
  float fh = __builtin_bit_cast(float, u & 0xffff0000u);
  float r = f - fh;
  l = (short)(unsigned short)(__builtin_bit_cast(unsigned int, r) >> 16);
}

__device__ __forceinline__ void load_split8(const float* __restrict__ p, bf16x8& h8, bf16x8& l8) {
  float4 a = *(const float4*)p;
  float4 b = *(const float4*)(p + 4);
  float f[8] = {a.x, a.y, a.z, a.w, b.x, b.y, b.z, b.w};
#pragma unroll
  for (int j = 0; j < 8; ++j) {
    short hh, ll;
    split_val(f[j], hh, ll);
    h8[j] = hh; l8[j] = ll;
  }
}

// ---------------- weight pre-split kernel ----------------
__global__ void prep_w(const float* __restrict__ Wq, const float* __restrict__ Wk,
                       const float* __restrict__ Wv, ushort_t* __restrict__ ws) {
  int idx = blockIdx.x * 256 + threadIdx.x;
  const float* src; int off; ushort_t *H, *L;
  if (idx < 8192)       { src = Wq; off = idx;         H = ws + WS_WQH; L = ws + WS_WQL; }
  else if (idx < 16384) { src = Wk; off = idx - 8192;  H = ws + WS_WKH; L = ws + WS_WKL; }
  else if (idx < 81920) { src = Wv; off = idx - 16384; H = ws + WS_WVH; L = ws + WS_WVL; }
  else return;
  short h, l;
  split_val(src[off], h, l);
  H[off] = (ushort_t)h;
  L[off] = (ushort_t)l;
}

// ---------------- main kernel ----------------
template<bool PW>
__global__ __launch_bounds__(256, 3) void xattn(
    const float* __restrict__ x1, const float* __restrict__ x2,
    const float* __restrict__ Wq, const float* __restrict__ bq,
    const float* __restrict__ Wk, const float* __restrict__ bk,
    const float* __restrict__ Wv, const float* __restrict__ bv,
    const ushort_t* __restrict__ wsp, float* __restrict__ out)
{
  __shared__ char smem[SMEM_BYTES];
  ushort_t* Xth  = (ushort_t*)(smem + OFF_XTH);
  ushort_t* Xtl  = (ushort_t*)(smem + OFF_XTL);
  float*    Xlin = (float*)(smem + OFF_R2);
  ushort_t* Kh   = (ushort_t*)(smem + OFF_KH);
  ushort_t* Kl   = (ushort_t*)(smem + OFF_KL);
  ushort_t* Vb   = (ushort_t*)(smem + OFF_R2);
  ushort_t* Ah   = (ushort_t*)(smem + OFF_AH);
  ushort_t* Al   = (ushort_t*)(smem + OFF_AL);
  ushort_t* Qh   = (ushort_t*)(smem + OFF_QH);
  ushort_t* Ql   = (ushort_t*)(smem + OFF_QL);

  const int tid  = threadIdx.x;
  const int lane = tid & 63;
  const int wv   = tid >> 6;
  const int l15  = lane & 15;
  const int g    = lane >> 4;

  const int grp = blockIdx.x;
  const int b   = grp >> 10;
  const int rem = grp & 1023;
  const int d   = rem >> 6;
  const int h   = rem & 63;
  const size_t base = (size_t)b * CDHW + (size_t)d * HW + (size_t)h * 64;

  const ushort_t* WqH = wsp + WS_WQH;
  const ushort_t* WqL = wsp + WS_WQL;
  const ushort_t* WkH = wsp + WS_WKH;
  const ushort_t* WkL = wsp + WS_WKL;
  const ushort_t* WvH = wsp + WS_WVH;
  const ushort_t* WvL = wsp + WS_WVL;

  // pass A: wave wv loads its 16 channels of the 64-channel tile, coalesced
  auto passA = [&](const float* __restrict__ src) {
#pragma unroll
    for (int i = 0; i < 4; ++i) {
      int ch = 16 * wv + (lane >> 4) + 4 * i;   // channel within tile
      int c4 = (lane & 15) << 2;                // x offset
      float4 v = *(const float4*)(src + (size_t)ch * DHW + c4);
      *(float4*)&Xlin[ch * XL_LD + c4] = v;
    }
  };
  // pass B: lane x transposes+splits the wave's 16 channels into Xth/Xtl
  auto passB = [&]() {
#pragma unroll
    for (int bb = 0; bb < 2; ++bb) {
      int c0 = 16 * wv + 8 * bb;
      bf16x8 h8, l8;
#pragma unroll
      for (int j = 0; j < 8; ++j) {
        float f = Xlin[(c0 + j) * XL_LD + lane];
        short hh, ll;
        split_val(f, hh, ll);
        h8[j] = hh; l8[j] = ll;
      }
      *(bf16x8*)&Xth[lane * XT_LD + c0] = h8;
      *(bf16x8*)&Xtl[lane * XT_LD + c0] = l8;
    }
  };

  // ===== loop 1: stream x1 c-tiles, accumulate Q^T (wave's x-quarter) =====
  {
    f32x4 qacc[2];
#pragma unroll
    for (int mt = 0; mt < 2; ++mt) {
      int r0 = mt * 16 + 4 * g;
      qacc[mt] = (f32x4){bq[r0], bq[r0 + 1], bq[r0 + 2], bq[r0 + 3]};
    }
    for (int t = 0; t < 4; ++t) {
      passA(x1 + base + (size_t)t * 64 * DHW);
      __syncthreads();
      passB();
      __syncthreads();
#pragma unroll
      for (int ks = 0; ks < 2; ++ks) {
        const int ko = ks * 32 + 8 * g;
        const int kg = t * 64 + ko;
        bf16x8 bh = *(const bf16x8*)&Xth[(16 * wv + l15) * XT_LD + ko];
        bf16x8 bl = *(const bf16x8*)&Xtl[(16 * wv + l15) * XT_LD + ko];
#pragma unroll
        for (int mt = 0; mt < 2; ++mt) {
          bf16x8 wh, wl;
          if constexpr (PW) {
            wh = *(const bf16x8*)&WqH[(size_t)(mt * 16 + l15) * 256 + kg];
            wl = *(const bf16x8*)&WqL[(size_t)(mt * 16 + l15) * 256 + kg];
          } else {
            load_split8(Wq + (size_t)(mt * 16 + l15) * 256 + kg, wh, wl);
          }
          qacc[mt] = MFMA16(wh, bh, qacc[mt]);
          qacc[mt] = MFMA16(wh, bl, qacc[mt]);
          qacc[mt] = MFMA16(wl, bh, qacc[mt]);
        }
      }
      __syncthreads();
    }
    // write Q split to R3: Qh[x][c8], x = wave's quarter
    const int x = 16 * wv + l15;
#pragma unroll
    for (int mt = 0; mt < 2; ++mt)
#pragma unroll
      for (int r = 0; r < 4; ++r) {
        short hh, ll;
        split_val(qacc[mt][r], hh, ll);
        Qh[x * QK_LD + mt * 16 + 4 * g + r] = (ushort_t)hh;
        Ql[x * QK_LD + mt * 16 + 4 * g + r] = (ushort_t)ll;
      }
  }

  // ===== loop 2: stream x2 c-tiles, accumulate K^T (wave's y-quarter) + V (wave's 64 c-rows) =====
  f32x4 vacc[4][4];
  {
    f32x4 kacc[2];
#pragma unroll
    for (int mt = 0; mt < 2; ++mt) {
      int r0 = mt * 16 + 4 * g;
      kacc[mt] = (f32x4){bk[r0], bk[r0 + 1], bk[r0 + 2], bk[r0 + 3]};
    }
#pragma unroll
    for (int mt = 0; mt < 4; ++mt) {
      int r0 = 64 * wv + mt * 16 + 4 * g;
      f32x4 bb = (f32x4){bv[r0], bv[r0 + 1], bv[r0 + 2], bv[r0 + 3]};
#pragma unroll
      for (int nt = 0; nt < 4; ++nt) vacc[mt][nt] = bb;
    }
    for (int t = 0; t < 4; ++t) {
      passA(x2 + base + (size_t)t * 64 * DHW);
      __syncthreads();
      passB();
      __syncthreads();
#pragma unroll
      for (int ks = 0; ks < 2; ++ks) {
        const int ko = ks * 32 + 8 * g;
        const int kg = t * 64 + ko;
        bf16x8 xh[4], xl[4];
#pragma unroll
        for (int nt = 0; nt < 4; ++nt) {
          xh[nt] = *(const bf16x8*)&Xth[(nt * 16 + l15) * XT_LD + ko];
          xl[nt] = *(const bf16x8*)&Xtl[(nt * 16 + l15) * XT_LD + ko];
        }
        // K (B-frag re-loaded explicitly: no runtime-indexed reg array)
        {
          bf16x8 bh = *(const bf16x8*)&Xth[(16 * wv + l15) * XT_LD + ko];
          bf16x8 bl = *(const bf16x8*)&Xtl[(16 * wv + l15) * XT_LD + ko];
#pragma unroll
          for (int mt = 0; mt < 2; ++mt) {
            bf16x8 wh, wl;
            if constexpr (PW) {
              wh = *(const bf16x8*)&WkH[(size_t)(mt * 16 + l15) * 256 + kg];
              wl = *(const bf16x8*)&WkL[(size_t)(mt * 16 + l15) * 256 + kg];
            } else {
              load_split8(Wk + (size_t)(mt * 16 + l15) * 256 + kg, wh, wl);
            }
            kacc[mt] = MFMA16(wh, bh, kacc[mt]);
            kacc[mt] = MFMA16(wh, bl, kacc[mt]);
            kacc[mt] = MFMA16(wl, bh, kacc[mt]);
          }
        }
        // V
#pragma unroll
        for (int mt = 0; mt < 4; ++mt) {
          bf16x8 wh, wl;
          if constexpr (PW) {
            wh = *(const bf16x8*)&WvH[(size_t)(64 * wv + mt * 16 + l15) * 256 + kg];
            wl = *(const bf16x8*)&WvL[(size_t)(64 * wv + mt * 16 + l15) * 256 + kg];
          } else {
            load_split8(Wv + (size_t)(64 * wv + mt * 16 + l15) * 256 + kg, wh, wl);
          }
#pragma unroll
          for (int nt = 0; nt < 4; ++nt) {
            vacc[mt][nt] = MFMA16(wh, xh[nt], vacc[mt][nt]);
            vacc[mt][nt] = MFMA16(wh, xl[nt], vacc[mt][nt]);
            vacc[mt][nt] = MFMA16(wl, xh[nt], vacc[mt][nt]);
          }
        }
      }
      __syncthreads();
    }
    // write K split to R2 (Xlin dead): Kh[y][c8]
    const int y = 16 * wv + l15;
#pragma unroll
    for (int mt = 0; mt < 2; ++mt)
#pragma unroll
      for (int r = 0; r < 4; ++r) {
        short hh, ll;
        split_val(kacc[mt][r], hh, ll);
        Kh[y * QK_LD + mt * 16 + 4 * g + r] = (ushort_t)hh;
        Kl[y * QK_LD + mt * 16 + 4 * g + r] = (ushort_t)ll;
      }
  }
  __syncthreads();

  // ===== phase 3: A = Q^T K (64x64), split-stored into R1 (Xth/Xtl dead) =====
  {
    const int y = 16 * wv + l15;
    bf16x8 kh = *(const bf16x8*)&Kh[y * QK_LD + 8 * g];
    bf16x8 kl = *(const bf16x8*)&Kl[y * QK_LD + 8 * g];
    f32x4 acc[4];
#pragma unroll
    for (int mt = 0; mt < 4; ++mt) acc[mt] = (f32x4){0.f, 0.f, 0.f, 0.f};
#pragma unroll
    for (int mt = 0; mt < 4; ++mt) {
      bf16x8 qh = *(const bf16x8*)&Qh[(mt * 16 + l15) * QK_LD + 8 * g];
      bf16x8 ql = *(const bf16x8*)&Ql[(mt * 16 + l15) * QK_LD + 8 * g];
      acc[mt] = MFMA16(qh, kh, acc[mt]);
      acc[mt] = MFMA16(qh, kl, acc[mt]);
      acc[mt] = MFMA16(ql, kh, acc[mt]);
    }
#pragma unroll
    for (int mt = 0; mt < 4; ++mt)
#pragma unroll
      for (int r = 0; r < 4; ++r) {
        short hh, ll;
        split_val(acc[mt][r], hh, ll);
        Ah[(mt * 16 + 4 * g + r) * A_LD + y] = (ushort_t)hh;
        Al[(mt * 16 + 4 * g + r) * A_LD + y] = (ushort_t)ll;
      }
  }
  __syncthreads();

  // ===== phase 4: Out = V * A^T, per 16-row c-tile via per-wave LDS round-trip =====
  {
    ushort_t* Vh = Vb + wv * 2304;   // [16][72] hi
    ushort_t* Vl = Vh + 1152;        // [16][72] lo
    const int cb = 64 * wv;
#pragma unroll
    for (int mt = 0; mt < 4; ++mt) {
#pragma unroll
      for (int nt = 0; nt < 4; ++nt)
#pragma unroll
        for (int r = 0; r < 4; ++r) {
          short hh, ll;
          split_val(vacc[mt][nt][r], hh, ll);
          Vh[(4 * g + r) * VB_LD + nt * 16 + l15] = (ushort_t)hh;
          Vl[(4 * g + r) * VB_LD + nt * 16 + l15] = (ushort_t)ll;
        }
      f32x4 oacc[4];
#pragma unroll
      for (int nt = 0; nt < 4; ++nt) oacc[nt] = (f32x4){0.f, 0.f, 0.f, 0.f};
#pragma unroll
      for (int ys = 0; ys < 2; ++ys) {
        const int yo = ys * 32 + 8 * g;
        bf16x8 vh8 = *(const bf16x8*)&Vh[l15 * VB_LD + yo];
        bf16x8 vl8 = *(const bf16x8*)&Vl[l15 * VB_LD + yo];
#pragma unroll
        for (int nt = 0; nt < 4; ++nt) {
          bf16x8 ah8 = *(const bf16x8*)&Ah[(nt * 16 + l15) * A_LD + yo];
          bf16x8 al8 = *(const bf16x8*)&Al[(nt * 16 + l15) * A_LD + yo];
          oacc[nt] = MFMA16(vh8, ah8, oacc[nt]);
          oacc[nt] = MFMA16(vh8, al8, oacc[nt]);
          oacc[nt] = MFMA16(vl8, ah8, oacc[nt]);
        }
      }
#pragma unroll
      for (int nt = 0; nt < 4; ++nt)
#pragma unroll
        for (int r = 0; r < 4; ++r)
          out[base + (size_t)(cb + mt * 16 + 4 * g + r) * DHW + nt * 16 + l15] = oacc[nt][r];
    }
  }
}

extern "C" void kernel_launch(void* const* d_in, const int* in_sizes, int n_in,
                              void* d_out, int out_size, void* d_ws, size_t ws_size,
                              hipStream_t stream)
{
  const float* x1 = (const float*)d_in[0];
  const float* x2 = (const float*)d_in[1];
  const float* Wq = (const float*)d_in[2];
  const float* bq = (const float*)d_in[3];
  const float* Wk = (const float*)d_in[4];
  const float* bk = (const float*)d_in[5];
  const float* Wv = (const float*)d_in[6];
  const float* bv = (const float*)d_in[7];
  float* out = (float*)d_out;

  const bool pw = (ws_size >= (size_t)WS_NEED_BYTES) && (d_ws != nullptr);
  if (pw) {
    ushort_t* ws = (ushort_t*)d_ws;
    hipLaunchKernelGGL(prep_w, dim3(320), dim3(256), 0, stream, Wq, Wk, Wv, ws);
    hipLaunchKernelGGL(xattn<true>, dim3(NB * ND * NH), dim3(256), 0, stream,
                       x1, x2, Wq, bq, Wk, bk, Wv, bv, ws, out);
  } else {
    hipLaunchKernelGGL(xattn<false>, dim3(NB * ND * NH), dim3(256), 0, stream,
                       x1, x2, Wq, bq, Wk, bk, Wv, bv, (const ushort_t*)nullptr, out);
  }
}